// Round 8
// baseline (640.334 us; speedup 1.0000x reference)
//
#include <hip/hip_runtime.h>
#include <math.h>

#pragma clang fp contract(off)

#define BB   8
#define NGT  60
#define LL   21504
#define CC   15
#define KTOP 13
#define BGI  15
#define EPSF 1e-9f
#define SSEG 12
#define SEGLEN (LL / SSEG)       // 1792 -> 28 elements per lane
#define NBLK 768                 // 3 blocks/CU guaranteed co-resident
#define NWAVES (NBLK * 4)        // 3072
#define NTASKS (BB * NGT * SSEG) // 5760 -> <=2 tasks per wave
#define NANCH_BLK (BB * LL / 256)  // 672
#define MAGIC 0x5A5B0000         // != 0xAAAAAAAA poison, per-round +r
#define SPIN_MAX 2000000         // bounded spin: fail, never hang

typedef unsigned long long u64;

// branchless descending compare-swap: ensures a >= b afterwards
#define CS(a, b) { u64 _hi = (b > a) ? b : a; u64 _lo = (b > a) ? a : b; a = _hi; b = _lo; }

__device__ __forceinline__ int aload_i(const int* p) {
    return __hip_atomic_load(p, __ATOMIC_RELAXED, __HIP_MEMORY_SCOPE_AGENT);
}
__device__ __forceinline__ unsigned aload_u(const unsigned* p) {
    return __hip_atomic_load(p, __ATOMIC_RELAXED, __HIP_MEMORY_SCOPE_AGENT);
}
__device__ __forceinline__ u64 aload_u64(const u64* p) {
    return __hip_atomic_load(p, __ATOMIC_RELAXED, __HIP_MEMORY_SCOPE_AGENT);
}

// Poison-tolerant grid barrier: block publishes flags[blk]=MAGIC+r (release,
// agent scope); block 0 polls all flags then publishes gen=MAGIC+r; everyone
// spins on gen. No initialization needed (poison != any MAGIC+r). Spin is
// bounded so a capacity-model error fails validation instead of hanging.
__device__ void grid_barrier(int* flags, int* gen, int r) {
    const int t = threadIdx.x;
    const int blk = blockIdx.x;
    __syncthreads();                          // block done with phase (drains vmcnt)
    if (t == 0) {
        __threadfence();                      // agent fence: wbl2 + inv
        __hip_atomic_store(&flags[blk], MAGIC + r, __ATOMIC_RELEASE,
                           __HIP_MEMORY_SCOPE_AGENT);
    }
    if (blk == 0) {
        for (int i = t; i < NBLK; i += 256) {
            int spins = 0;
            while (__hip_atomic_load(&flags[i], __ATOMIC_ACQUIRE,
                                     __HIP_MEMORY_SCOPE_AGENT) != MAGIC + r) {
                if (++spins > SPIN_MAX) break;
                __builtin_amdgcn_s_sleep(2);
            }
        }
        __syncthreads();
        if (t == 0)
            __hip_atomic_store(gen, MAGIC + r, __ATOMIC_RELEASE,
                               __HIP_MEMORY_SCOPE_AGENT);
    }
    if (t == 0) {
        int spins = 0;
        while (__hip_atomic_load(gen, __ATOMIC_ACQUIRE,
                                 __HIP_MEMORY_SCOPE_AGENT) != MAGIC + r) {
            if (++spins > SPIN_MAX) break;
            __builtin_amdgcn_s_sleep(2);
        }
        __threadfence();                      // acquire side: invalidate caches
    }
    __syncthreads();
}

// AABB of rotated box, replicating reference _box_min_max op order.
__device__ __forceinline__ float4 rbox_aabb(float cx, float cy, float w, float h, float r) {
    float cr = (float)cos((double)r);
    float sr = (float)sin((double)r);
    float dx = (w * 0.5f) * cr;
    float dy = (h * 0.5f) * sr;
    float xs[4] = {cx - dx, cx + dx, cx + dx, cx - dx};
    float ys[4] = {cy - dy, cy - dy, cy + dy, cy + dy};
    float mnx = 1e30f, mxx = -1e30f, mny = 1e30f, mxy = -1e30f;
#pragma unroll
    for (int k = 0; k < 4; ++k) {
        float tx = xs[k] - cx, ty = ys[k] - cy;
        float xr = (cx + tx * cr) - ty * sr;
        float yr = (cy + tx * sr) + ty * cr;
        mnx = fminf(mnx, xr); mxx = fmaxf(mxx, xr);
        mny = fminf(mny, yr); mxy = fmaxf(mxy, yr);
    }
    return make_float4(mnx, mxx, mny, mxy);
}

__device__ __forceinline__ float iou_pair(float4 g, float a1, float4 p, float a2) {
    float iw = fmaxf(fminf(g.y, p.y) - fmaxf(g.x, p.x), 0.0f);
    float ih = fmaxf(fminf(g.w, p.w) - fmaxf(g.z, p.z), 0.0f);
    float inter = iw * ih;
    float denom = ((a1 + a2) - inter) + EPSF;
    float q = inter / denom;
    return fminf(fmaxf(q, 0.0f), 1.0f);
}

struct Params {
    const float* pr;      // pred_rboxes (B,L,5)
    const float* ps;      // pred_scores (B,L,C)
    const float* anch;    // anchor_points (L,2)
    const int*   labels;  // gt_labels (B,n)
    const float* gt;      // gt_bboxes (B,n,5)
    const int*   crowd;   // gt_crowd (B,n)
    const float* pad;     // pad_gt_mask (B,n)
    float* out;
    float4* pbox;  float* parea;
    float4* gbox;  float4* gtrig;  float4* ggeom;
    int* cnt;  int* claim;
    unsigned* maxM;  unsigned* maxI;
    int* assigned;  float* aMetric;
    u64* candK;
    int* flags;  int* gen;
};

__global__ __launch_bounds__(256, 3) void mega_kernel(Params P) {
    __shared__ float lds[CC * 257];
    __shared__ u64 sk[4];
    __shared__ u64 swin;
    __shared__ float4 sB[NGT];
    __shared__ float  sA[NGT];

    const int t = threadIdx.x;
    const int blk = blockIdx.x;

    // ========== P0: prep (pred boxes via LDS transpose, gt state, zeroing) ==========
    if (blk < NANCH_BLK) {
        const int b = blk / (LL / 256);
        const int j0 = (blk % (LL / 256)) * 256;
        const int i = blk * 256 + t;
        const float* prb = P.pr + (size_t)(b * LL + j0) * 5;
#pragma unroll
        for (int k = 0; k < 5; ++k) {
            int g = k * 256 + t;
            lds[(g % 5) * 257 + g / 5] = prb[g];
        }
        __syncthreads();
        float cx = lds[0 * 257 + t], cy = lds[1 * 257 + t];
        float w  = lds[2 * 257 + t], h  = lds[3 * 257 + t], r = lds[4 * 257 + t];
        P.pbox[i]  = rbox_aabb(cx, cy, w, h, r);
        P.parea[i] = w * h;
        P.cnt[i] = 0; P.claim[i] = 0;
        if (i < BB * NGT) {
            float gcx = P.gt[i * 5 + 0], gcy = P.gt[i * 5 + 1];
            float gw  = P.gt[i * 5 + 2], gh  = P.gt[i * 5 + 3], gr = P.gt[i * 5 + 4];
            P.gbox[i] = rbox_aabb(gcx, gcy, gw, gh, gr);
            float gcr = (float)cos((double)gr);
            float gsr = (float)sin((double)gr);
            P.gtrig[i] = make_float4(gcr, gsr, gw * gh, P.pad[i]);
            P.ggeom[i] = make_float4(gcx, gcy, gw * 0.5f, gh * 0.5f);
            P.maxM[i] = 0u; P.maxI[i] = 0u;
        }
    }
    grid_barrier(P.flags, P.gen, 0);

    // ========== P1: per-(row,segment) top-13 scan, <=2 tasks per wave ==========
    {
        const int wave = (blk << 2) | (t >> 6);
        const int lane = t & 63;
        const float2* an2 = (const float2*)P.anch;
        for (int task = wave; task < NTASKS; task += NWAVES) {
            int bi = task / SSEG, s = task % SSEG;
            float4 tg = P.gtrig[bi];
            if (tg.w == 0.0f) continue;       // padded gt (wave-uniform)
            int b = bi / NGT;
            float4 g  = P.gbox[bi];
            float4 gg = P.ggeom[bi];
            float  a1 = tg.z;
            const float*  srow = P.ps + (size_t)b * LL * CC + P.labels[bi];
            const float4* pb   = P.pbox + (size_t)b * LL;
            const float*  pa   = P.parea + (size_t)b * LL;

            u64 k0 = 0, k1 = 0, k2 = 0, k3 = 0, k4 = 0, k5 = 0, k6 = 0,
                k7 = 0, k8 = 0, k9 = 0, k10 = 0, k11 = 0, k12 = 0;

            int base = s * SEGLEN;
            for (int e = lane; e < SEGLEN; e += 64) {
                int j = base + e;
                float2 ap = an2[j];
                float dx = ap.x - gg.x, dy = ap.y - gg.y;
                float xl = dx * tg.x + dy * tg.y;
                float yl = dy * tg.x - dx * tg.y;
                bool ing = (fabsf(xl) <= gg.z) && (fabsf(yl) <= gg.w);
                float v = 0.0f;
                if (__ballot(ing)) {          // wave-uniform fast-path skip
                    float4 p = pb[j];
                    float a2 = pa[j];
                    float iou = iou_pair(g, a1, p, a2);
                    float i2 = iou * iou;
                    v = ing ? (srow[(size_t)j * CC] * (i2 * i2 * i2)) : 0.0f;
                }
                // key = (v_bits << 32) | ~j : one u64 desc compare ==
                // (value desc, index asc) == jax.lax.top_k stable order
                u64 key = ((u64)__float_as_uint(v) << 32) | (unsigned)(~j);
                if (key > k12) {
                    k12 = key;
                    CS(k11, k12); CS(k10, k11); CS(k9, k10); CS(k8, k9);
                    CS(k7, k8);   CS(k6, k7);   CS(k5, k6);  CS(k4, k5);
                    CS(k3, k4);   CS(k2, k3);   CS(k1, k2);  CS(k0, k1);
                }
            }

            // 13-round butterfly merge over the 64 sorted-list heads
            size_t outIdx = (size_t)task * KTOP;
            for (int r = 0; r < KTOP; ++r) {
                u64 ov = k0;
#pragma unroll
                for (int off = 32; off > 0; off >>= 1) {
                    u64 v2 = __shfl_xor(ov, off, 64);
                    if (v2 > ov) ov = v2;
                }
                if (lane == 0) P.candK[outIdx + r] = ov;
                if (k0 == ov) {       // keys unique -> exactly one lane pops
                    k0 = k1; k1 = k2; k2 = k3; k3 = k4; k4 = k5; k5 = k6;
                    k6 = k7; k7 = k8; k8 = k9; k9 = k10; k10 = k11; k11 = k12;
                    k12 = 0;
                }
            }
        }
    }
    grid_barrier(P.flags, P.gen, 1);

    // ========== P2: merge 12x13 candidates per row -> claims ==========
    if (blk < BB * NGT) {
        int bi = blk;
        float4 tg = P.gtrig[bi];
        if (tg.w != 0.0f) {
            int b = bi / NGT, i = bi % NGT;
            float4 gg = P.ggeom[bi];
            u64 myk = 0;
            if (t < SSEG * KTOP)
                myk = aload_u64(&P.candK[(size_t)bi * SSEG * KTOP + t]);
            for (int r = 0; r < KTOP; ++r) {
                u64 ov = myk;
#pragma unroll
                for (int off = 32; off > 0; off >>= 1) {
                    u64 v2 = __shfl_xor(ov, off, 64);
                    if (v2 > ov) ov = v2;
                }
                if ((t & 63) == 0) sk[t >> 6] = ov;
                __syncthreads();
                if (t == 0) {
                    u64 bk = sk[0];
#pragma unroll
                    for (int k = 1; k < 4; ++k) if (sk[k] > bk) bk = sk[k];
                    swin = bk;
                    unsigned vb = (unsigned)(bk >> 32);
                    int j = (int)(~(unsigned)bk);
                    bool in = (vb != 0);      // v > 0 implies in_gts
                    if (!in) {                // zero-metric pick: explicit test
                        float2 ap = ((const float2*)P.anch)[j];
                        float dx = ap.x - gg.x, dy = ap.y - gg.y;
                        float xl = dx * tg.x + dy * tg.y;
                        float yl = dy * tg.x - dx * tg.y;
                        in = (fabsf(xl) <= gg.z) && (fabsf(yl) <= gg.w);
                    }
                    if (in) {
                        atomicAdd(&P.cnt[b * LL + j], 1);
                        atomicMax(&P.claim[b * LL + j], i);
                    }
                }
                __syncthreads();
                if (myk == swin) myk = 0;     // consume winner (keys unique)
            }
        }
    }
    grid_barrier(P.flags, P.gen, 2);

    // ========== P3: resolve assignments + per-gt maxes ==========
    if (blk < NANCH_BLK) {
        const int b = blk / (LL / 256);
        if (t < NGT) { sB[t] = P.gbox[b * NGT + t]; sA[t] = P.gtrig[b * NGT + t].z; }
        __syncthreads();
        int p = blk * 256 + t;
        int c = aload_i(&P.cnt[p]);
        int a = -1; float m = 0.0f;
        if (c > 0) {
            float4 pb = P.pbox[p];
            float a2 = P.parea[p];
            float iouv;
            if (c == 1) {
                a = aload_i(&P.claim[p]);
                iouv = iou_pair(sB[a], sA[a], pb, a2);
            } else {
                float best = -1.0f; int bi = 0;
                for (int i = 0; i < NGT; ++i) {
                    float v = iou_pair(sB[i], sA[i], pb, a2);
                    if (v > best) { best = v; bi = i; }  // ties -> lowest index
                }
                a = bi; iouv = best;
            }
            float sc = P.ps[(size_t)p * CC + P.labels[b * NGT + a]];
            float i2 = iouv * iouv;
            m = sc * (i2 * i2 * i2);
            atomicMax(&P.maxM[b * NGT + a], __float_as_uint(m));
            atomicMax(&P.maxI[b * NGT + a], __float_as_uint(iouv));
        }
        P.assigned[p] = a;                    // same-block consumer (P4)
        P.aMetric[p] = m;
    }
    grid_barrier(P.flags, P.gen, 3);

    // ========== P4: finalize (5 outputs; strided via LDS transpose) ==========
    if (blk < NANCH_BLK) {
        const int b = blk / (LL / 256);
        const int j0 = (blk % (LL / 256)) * 256;
        const int p = blk * 256 + t;
        const size_t O0 = 0;
        const size_t O1 = (size_t)BB * LL;
        const size_t O2 = O1 + (size_t)BB * LL * 5;
        const size_t O3 = O2 + (size_t)BB * LL * CC;
        const size_t O4 = O3 + (size_t)BB * LL;

        int a = P.assigned[p];
        bool pos = (a >= 0);
        int idx = pos ? a : 0;
        int lab = P.labels[b * NGT + idx];
        int cw  = P.crowd[b * NGT + idx];
        P.out[O0 + p] = pos ? (float)lab : (float)BGI;
        P.out[O3 + p] = (float)idx;
        P.out[O4 + p] = (float)cw;
        float per = 0.0f;
        if (pos) {
            float mm = __uint_as_float(aload_u(&P.maxM[b * NGT + a]));
            float mi = __uint_as_float(aload_u(&P.maxI[b * NGT + a]));
            per = P.aMetric[p] / (mm + EPSF) * mi;
        }

        // assigned_scores (stride-15) via +1-padded LDS transpose
        float keep = (pos && cw == 0) ? per : 0.0f;
#pragma unroll
        for (int c = 0; c < CC; ++c)
            lds[c * 257 + t] = (c == lab) ? keep : 0.0f;
        __syncthreads();
        float* o2 = P.out + O2 + (size_t)(b * LL + j0) * CC;
#pragma unroll
        for (int k = 0; k < CC; ++k) {
            int g = k * 256 + t;
            o2[g] = lds[(g % CC) * 257 + g / CC];
        }
        __syncthreads();

        // assigned_rboxes (stride-5) via LDS transpose
        const float* gb = P.gt + (size_t)(b * NGT + idx) * 5;
#pragma unroll
        for (int k = 0; k < 5; ++k)
            lds[k * 257 + t] = gb[k];
        __syncthreads();
        float* o1 = P.out + O1 + (size_t)(b * LL + j0) * 5;
#pragma unroll
        for (int k = 0; k < 5; ++k) {
            int g = k * 256 + t;
            o1[g] = lds[(g % 5) * 257 + g / 5];
        }
    }
}

extern "C" void kernel_launch(void* const* d_in, const int* in_sizes, int n_in,
                              void* d_out, int out_size, void* d_ws, size_t ws_size,
                              hipStream_t stream) {
    char* ws = (char*)d_ws;
    size_t off = 0;
    auto alloc = [&](size_t bytes) {
        void* pp = ws + off;
        off += (bytes + 255) & ~(size_t)255;
        return pp;
    };

    Params P;
    P.ps     = (const float*)d_in[0];
    P.pr     = (const float*)d_in[1];
    P.anch   = (const float*)d_in[2];
    P.labels = (const int*)d_in[3];
    P.gt     = (const float*)d_in[4];
    // d_in[5] = gt_poses (unused)
    P.crowd  = (const int*)d_in[6];
    P.pad    = (const float*)d_in[7];
    P.out    = (float*)d_out;

    P.pbox     = (float4*)alloc((size_t)BB * LL * 16);
    P.parea    = (float*)alloc((size_t)BB * LL * 4);
    P.gbox     = (float4*)alloc((size_t)BB * NGT * 16);
    P.gtrig    = (float4*)alloc((size_t)BB * NGT * 16);
    P.ggeom    = (float4*)alloc((size_t)BB * NGT * 16);
    P.cnt      = (int*)alloc((size_t)BB * LL * 4);
    P.claim    = (int*)alloc((size_t)BB * LL * 4);
    P.maxM     = (unsigned*)alloc((size_t)BB * NGT * 4);
    P.maxI     = (unsigned*)alloc((size_t)BB * NGT * 4);
    P.assigned = (int*)alloc((size_t)BB * LL * 4);
    P.aMetric  = (float*)alloc((size_t)BB * LL * 4);
    P.candK    = (u64*)alloc((size_t)NTASKS * KTOP * 8);
    P.flags    = (int*)alloc((size_t)NBLK * 4);
    P.gen      = (int*)alloc(4);

    mega_kernel<<<dim3(NBLK), dim3(256), 0, stream>>>(P);
}

// Round 10
// 278.619 us; speedup vs baseline: 2.2982x; 2.2982x over previous
//
#include <hip/hip_runtime.h>
#include <math.h>

#pragma clang fp contract(off)

#define BB   8
#define NGT  60
#define LL   21504
#define CC   15
#define KTOP 13
#define BGI  15
#define EPSF 1e-9f
#define NROWBLK 120            // 4 rows per block (1 wave per row)
#define LISTCAP 16384
#define NANCH_BLK (BB * LL / 256)  // 672

typedef unsigned long long u64;

// branchless descending compare-swap: ensures a >= b afterwards
#define CS(a, b) { u64 _hi = (b > a) ? b : a; u64 _lo = (b > a) ? a : b; a = _hi; b = _lo; }

// AABB of rotated box, replicating reference _box_min_max op order.
// NOTE: this is the reference's QUIRK box (pre-corners (+-w/2*cos, +-h/2*sin)),
// used for IoU only. It does NOT bound the in_gts support -- the true rotated
// rect is wider (R9 bug). Scan windows must use ex/ey below, not this box.
__device__ __forceinline__ float4 rbox_aabb(float cx, float cy, float w, float h, float r) {
    float cr = (float)cos((double)r);
    float sr = (float)sin((double)r);
    float dx = (w * 0.5f) * cr;
    float dy = (h * 0.5f) * sr;
    float xs[4] = {cx - dx, cx + dx, cx + dx, cx - dx};
    float ys[4] = {cy - dy, cy - dy, cy + dy, cy + dy};
    float mnx = 1e30f, mxx = -1e30f, mny = 1e30f, mxy = -1e30f;
#pragma unroll
    for (int k = 0; k < 4; ++k) {
        float tx = xs[k] - cx, ty = ys[k] - cy;
        float xr = (cx + tx * cr) - ty * sr;
        float yr = (cy + tx * sr) + ty * cr;
        mnx = fminf(mnx, xr); mxx = fmaxf(mxx, xr);
        mny = fminf(mny, yr); mxy = fmaxf(mxy, yr);
    }
    return make_float4(mnx, mxx, mny, mxy);
}

__device__ __forceinline__ float iou_pair(float4 g, float a1, float4 p, float a2) {
    float iw = fmaxf(fminf(g.y, p.y) - fmaxf(g.x, p.x), 0.0f);
    float ih = fmaxf(fminf(g.w, p.w) - fmaxf(g.z, p.z), 0.0f);
    float inter = iw * ih;
    float denom = ((a1 + a2) - inter) + EPSF;
    float q = inter / denom;
    return fminf(fmaxf(q, 0.0f), 1.0f);
}

// in-gts test, reference op order (anchor coords analytic, exact in fp32)
__device__ __forceinline__ bool in_gts(float apx, float apy, float4 gg, float4 tg) {
    float dx = apx - gg.x, dy = apy - gg.y;
    float xl = dx * tg.x + dy * tg.y;
    float yl = dy * tg.x - dx * tg.y;
    return (fabsf(xl) <= gg.z) && (fabsf(yl) <= gg.w);
}

// ---------- prep: pred boxes (LDS-coalesced), gt state, zero-init ----------
__global__ __launch_bounds__(256) void prep_kernel(
        const float* __restrict__ pr,
        const float* __restrict__ gt,
        const float* __restrict__ pad,
        float4* __restrict__ pbox,
        float* __restrict__ parea,
        float4* __restrict__ gbox,
        float4* __restrict__ gtrig,
        float4* __restrict__ ggeom,
        int* __restrict__ cnt,
        int* __restrict__ nclaims,
        int* __restrict__ done) {
    __shared__ float lds[5 * 257];
    const int t = threadIdx.x;
    const int b = blockIdx.x / (LL / 256);
    const int j0 = (blockIdx.x % (LL / 256)) * 256;
    const int i = blockIdx.x * 256 + t;

    const float* prb = pr + (size_t)(b * LL + j0) * 5;
#pragma unroll
    for (int k = 0; k < 5; ++k) {
        int g = k * 256 + t;
        lds[(g % 5) * 257 + g / 5] = prb[g];
    }
    __syncthreads();
    float cx = lds[0 * 257 + t], cy = lds[1 * 257 + t];
    float w  = lds[2 * 257 + t], h  = lds[3 * 257 + t], r = lds[4 * 257 + t];
    pbox[i]  = rbox_aabb(cx, cy, w, h, r);
    parea[i] = w * h;
    cnt[i] = 0;
    if (i == 0) { *nclaims = 0; *done = 0; }
    if (i < BB * NGT) {
        float gcx = gt[i * 5 + 0], gcy = gt[i * 5 + 1];
        float gw  = gt[i * 5 + 2], gh  = gt[i * 5 + 3], gr = gt[i * 5 + 4];
        gbox[i] = rbox_aabb(gcx, gcy, gw, gh, gr);
        float gcr = (float)cos((double)gr);
        float gsr = (float)sin((double)gr);
        gtrig[i] = make_float4(gcr, gsr, gw * gh, pad[i]);
        ggeom[i] = make_float4(gcx, gcy, gw * 0.5f, gh * 0.5f);
    }
}

// ---------- topk+claims (true-support window) + last-block sparse resolve ----------
// One wave per GT row. Positives (metric>0) require in_gts, whose support is
// the TRUE rotated rect: half-extents ex=(w/2)|cos|+(h/2)|sin|,
// ey=(w/2)|sin|+(h/2)|cos| around (cx,cy). Window span <= 58 cells < 64 lanes.
// Zero-metric top-k slots are filled with globally-lowest-index non-positive
// anchors (claimed only if in-gts) -- exact jax.lax.top_k emulation.
__global__ __launch_bounds__(256) void topk_claim_kernel(
        const float* __restrict__ ps,
        const int* __restrict__ labels,
        const float4* __restrict__ pbox,
        const float* __restrict__ parea,
        const float4* __restrict__ gbox,
        const float4* __restrict__ gtrig,
        const float4* __restrict__ ggeom,
        int* __restrict__ cnt,
        int* __restrict__ list,
        int* __restrict__ nclaims,
        int* __restrict__ done,
        int* __restrict__ assigned,
        float* __restrict__ aMetric,
        unsigned* __restrict__ maxM,
        unsigned* __restrict__ maxI) {
    __shared__ int posjS[4][KTOP];
    __shared__ int islast;
    __shared__ unsigned mMs[BB * NGT], mIs[BB * NGT];
    const int t = threadIdx.x;
    const int w = t >> 6, lane = t & 63;
    const int bi = blockIdx.x * 4 + w;          // 480 rows
    const int b = bi / NGT, i = bi % NGT;

    float4 tg = gtrig[bi];
    if (tg.w != 0.0f) {                          // padded rows: no claims
        float4 g  = gbox[bi];
        float4 gg = ggeom[bi];
        float  a1 = tg.z;
        const float*  srow = ps + (size_t)b * LL * CC + labels[bi];
        const float4* pb   = pbox + (size_t)b * LL;
        const float*  pa   = parea + (size_t)b * LL;

        // true in_gts support half-extents (R9 fix: NOT the quirk AABB)
        float aco = fabsf(tg.x), asi = fabsf(tg.y);
        float ex = gg.z * aco + gg.w * asi;
        float ey = gg.z * asi + gg.w * aco;

        u64 k0 = 0, k1 = 0, k2 = 0, k3 = 0, k4 = 0, k5 = 0, k6 = 0,
            k7 = 0, k8 = 0, k9 = 0, k10 = 0, k11 = 0, k12 = 0;

        // scan the 3 anchor-grid windows covering the true support
#pragma unroll
        for (int sc3 = 0; sc3 < 3; ++sc3) {
            const int gsz  = 128 >> sc3;                     // 128,64,32
            const float st = (float)(8 << sc3);              // 8,16,32
            const int base = (sc3 == 0) ? 0 : (sc3 == 1 ? 16384 : 20480);
            int ix_lo = max(0,       (int)floorf((gg.x - ex) / st - 0.5f) - 1);
            int ix_hi = min(gsz - 1, (int)ceilf ((gg.x + ex) / st - 0.5f) + 1);
            int iy_lo = max(0,       (int)floorf((gg.y - ey) / st - 0.5f) - 1);
            int iy_hi = min(gsz - 1, (int)ceilf ((gg.y + ey) / st - 0.5f) + 1);
            int ix = ix_lo + lane;                           // span <= 58 < 64
            if (ix <= ix_hi) {
                float apx = (ix + 0.5f) * st;
                for (int iy = iy_lo; iy <= iy_hi; ++iy) {
                    int j = base + iy * gsz + ix;
                    float apy = (iy + 0.5f) * st;
                    bool ing = in_gts(apx, apy, gg, tg);
                    float4 p = pb[j];
                    float a2 = pa[j];
                    float iou = iou_pair(g, a1, p, a2);
                    float i2 = iou * iou;
                    float v = ing ? (srow[(size_t)j * CC] * (i2 * i2 * i2)) : 0.0f;
                    if (v > 0.0f) {                          // positives only
                        u64 key = ((u64)__float_as_uint(v) << 32) | (unsigned)(~j);
                        if (key > k12) {
                            k12 = key;
                            CS(k11, k12); CS(k10, k11); CS(k9, k10); CS(k8, k9);
                            CS(k7, k8);   CS(k6, k7);   CS(k5, k6);  CS(k4, k5);
                            CS(k3, k4);   CS(k2, k3);   CS(k1, k2);  CS(k0, k1);
                        }
                    }
                }
            }
        }

        // merge top-13 positives across the wave; claim them
        int n_pos = 0;
        for (int r = 0; r < KTOP; ++r) {
            u64 ov = k0;
#pragma unroll
            for (int off = 32; off > 0; off >>= 1) {
                u64 v2 = __shfl_xor(ov, off, 64);
                if (v2 > ov) ov = v2;
            }
            if (ov != 0) {                       // positive pick (keys>0 iff v>0)
                int j = (int)(~(unsigned)ov);
                if (lane == 0) {
                    posjS[w][n_pos] = j;
                    int p2 = b * LL + j;
                    atomicAdd(&cnt[p2], 1);
                    int slot = atomicAdd(nclaims, 1);
                    if (slot < LISTCAP)
                        __hip_atomic_store(&list[slot], (bi << 18) | p2,
                                           __ATOMIC_RELAXED, __HIP_MEMORY_SCOPE_AGENT);
                }
                n_pos++;
                if (k0 == ov) {                  // unique -> one lane pops
                    k0 = k1; k1 = k2; k2 = k3; k3 = k4; k4 = k5; k5 = k6;
                    k6 = k7; k7 = k8; k8 = k9; k9 = k10; k10 = k11; k11 = k12;
                    k12 = 0;
                }
            }
        }
        // zero-metric slots: globally-lowest-index non-positive anchors,
        // claimed iff in-gts (exact reference semantics). Terminates after
        // ~KTOP iterations: low-index anchors are almost never positive.
        if (lane == 0 && n_pos < KTOP) {
            int need = KTOP - n_pos;
            for (int jz = 0; need > 0 && jz < LL; ++jz) {
                bool isPos = false;
                for (int k = 0; k < n_pos; ++k) isPos |= (posjS[w][k] == jz);
                if (isPos) continue;
                need--;
                int ix, iy; float st2;
                if (jz < 16384)      { ix = jz & 127; iy = jz >> 7; st2 = 8.f; }
                else if (jz < 20480) { int e = jz - 16384; ix = e & 63; iy = e >> 6; st2 = 16.f; }
                else                 { int e = jz - 20480; ix = e & 31; iy = e >> 5; st2 = 32.f; }
                float apx = (ix + 0.5f) * st2, apy = (iy + 0.5f) * st2;
                if (in_gts(apx, apy, gg, tg)) {
                    int p2 = b * LL + jz;
                    atomicAdd(&cnt[p2], 1);
                    int slot = atomicAdd(nclaims, 1);
                    if (slot < LISTCAP)
                        __hip_atomic_store(&list[slot], (bi << 18) | p2,
                                           __ATOMIC_RELAXED, __HIP_MEMORY_SCOPE_AGENT);
                }
            }
        }
    }

    // ---- elect last block (all claims of all blocks are at MALL by now) ----
    __syncthreads();                             // drains this block's vmcnt
    if (t == 0) islast = (atomicAdd(done, 1) == NROWBLK - 1);
    __syncthreads();

    // ---- tail: sparse resolve over the claim list ----
    if (islast) {
        for (int k = t; k < BB * NGT; k += 256) { mMs[k] = 0u; mIs[k] = 0u; }
        __syncthreads();
        int n = __hip_atomic_load(nclaims, __ATOMIC_RELAXED, __HIP_MEMORY_SCOPE_AGENT);
        n = min(n, LISTCAP);
        for (int e = t; e < n; e += 256) {
            int val = __hip_atomic_load(&list[e], __ATOMIC_RELAXED, __HIP_MEMORY_SCOPE_AGENT);
            int p = val & 0x3FFFF;
            int bic = val >> 18;
            int bb = p / LL;
            int c = __hip_atomic_load(&cnt[p], __ATOMIC_RELAXED, __HIP_MEMORY_SCOPE_AGENT);
            float4 pbv = pbox[p];
            float a2 = parea[p];
            int a; float iouv;
            if (c == 1) {
                a = bic - bb * NGT;
                iouv = iou_pair(gbox[bb * NGT + a], gtrig[bb * NGT + a].z, pbv, a2);
            } else {
                float best = -1.0f; int bsti = 0;
                for (int ii = 0; ii < NGT; ++ii) {
                    float v = iou_pair(gbox[bb * NGT + ii], gtrig[bb * NGT + ii].z, pbv, a2);
                    if (v > best) { best = v; bsti = ii; }   // ties -> lowest index
                }
                a = bsti; iouv = best;
            }
            float sc = ps[(size_t)p * CC + labels[bb * NGT + a]];
            float i2 = iouv * iouv;
            float m = sc * (i2 * i2 * i2);
            assigned[p] = a;                     // consumed next dispatch (plain ok)
            aMetric[p] = m;
            atomicMax(&mMs[bb * NGT + a], __float_as_uint(m));
            atomicMax(&mIs[bb * NGT + a], __float_as_uint(iouv));
        }
        __syncthreads();
        for (int k = t; k < BB * NGT; k += 256) { maxM[k] = mMs[k]; maxI[k] = mIs[k]; }
    }
}

// ---------- finalize: all 5 outputs; strided regions via LDS transpose ----------
__global__ __launch_bounds__(256) void finalize_kernel(
        const float* __restrict__ gt,
        const int* __restrict__ labels,
        const int* __restrict__ crowd,
        const int* __restrict__ cnt,
        const int* __restrict__ assigned,
        const float* __restrict__ aMetric,
        const unsigned* __restrict__ maxM,
        const unsigned* __restrict__ maxI,
        float* __restrict__ out) {
    __shared__ float lds[CC * 257];
    const int t = threadIdx.x;
    const int b = blockIdx.x / (LL / 256);
    const int j0 = (blockIdx.x % (LL / 256)) * 256;
    const int p = blockIdx.x * 256 + t;
    const size_t O0 = 0;
    const size_t O1 = (size_t)BB * LL;
    const size_t O2 = O1 + (size_t)BB * LL * 5;
    const size_t O3 = O2 + (size_t)BB * LL * CC;
    const size_t O4 = O3 + (size_t)BB * LL;

    bool pos = (cnt[p] > 0);
    int idx = pos ? assigned[p] : 0;
    int lab = labels[b * NGT + idx];
    int cw  = crowd[b * NGT + idx];
    out[O0 + p] = pos ? (float)lab : (float)BGI;
    out[O3 + p] = (float)idx;
    out[O4 + p] = (float)cw;
    float per = 0.0f;
    if (pos) {
        float mm = __uint_as_float(maxM[b * NGT + idx]);
        float mi = __uint_as_float(maxI[b * NGT + idx]);
        per = aMetric[p] / (mm + EPSF) * mi;
    }

    // assigned_scores (stride-15) via +1-padded LDS transpose
    float keep = (pos && cw == 0) ? per : 0.0f;
#pragma unroll
    for (int c = 0; c < CC; ++c)
        lds[c * 257 + t] = (c == lab) ? keep : 0.0f;
    __syncthreads();
    float* o2 = out + O2 + (size_t)(b * LL + j0) * CC;
#pragma unroll
    for (int k = 0; k < CC; ++k) {
        int g = k * 256 + t;
        o2[g] = lds[(g % CC) * 257 + g / CC];
    }
    __syncthreads();

    // assigned_rboxes (stride-5) via LDS transpose
    const float* gb = gt + (size_t)(b * NGT + idx) * 5;
#pragma unroll
    for (int k = 0; k < 5; ++k)
        lds[k * 257 + t] = gb[k];
    __syncthreads();
    float* o1 = out + O1 + (size_t)(b * LL + j0) * 5;
#pragma unroll
    for (int k = 0; k < 5; ++k) {
        int g = k * 256 + t;
        o1[g] = lds[(g % 5) * 257 + g / 5];
    }
}

extern "C" void kernel_launch(void* const* d_in, const int* in_sizes, int n_in,
                              void* d_out, int out_size, void* d_ws, size_t ws_size,
                              hipStream_t stream) {
    const float* pred_scores = (const float*)d_in[0];
    const float* pred_rboxes = (const float*)d_in[1];
    // d_in[2] = anchor_points (analytic now, unused)
    const int*   gt_labels   = (const int*)d_in[3];
    const float* gt_bboxes   = (const float*)d_in[4];
    // d_in[5] = gt_poses (unused)
    const int*   gt_crowd    = (const int*)d_in[6];
    const float* pad_gt      = (const float*)d_in[7];
    float* out = (float*)d_out;

    char* ws = (char*)d_ws;
    size_t off = 0;
    auto alloc = [&](size_t bytes) {
        void* pp = ws + off;
        off += (bytes + 255) & ~(size_t)255;
        return pp;
    };
    float4* pbox  = (float4*)alloc((size_t)BB * LL * 16);
    float*  parea = (float*)alloc((size_t)BB * LL * 4);
    float4* gbox  = (float4*)alloc((size_t)BB * NGT * 16);
    float4* gtrig = (float4*)alloc((size_t)BB * NGT * 16);
    float4* ggeom = (float4*)alloc((size_t)BB * NGT * 16);
    int* cnt        = (int*)alloc((size_t)BB * LL * 4);
    int*   assigned = (int*)alloc((size_t)BB * LL * 4);
    float* aMetric  = (float*)alloc((size_t)BB * LL * 4);
    unsigned* maxM  = (unsigned*)alloc((size_t)BB * NGT * 4);
    unsigned* maxI  = (unsigned*)alloc((size_t)BB * NGT * 4);
    int* list       = (int*)alloc((size_t)LISTCAP * 4);
    int* nclaims    = (int*)alloc(256);
    int* done       = (int*)alloc(256);

    prep_kernel<<<dim3(NANCH_BLK), dim3(256), 0, stream>>>(
        pred_rboxes, gt_bboxes, pad_gt,
        pbox, parea, gbox, gtrig, ggeom, cnt, nclaims, done);
    topk_claim_kernel<<<dim3(NROWBLK), dim3(256), 0, stream>>>(
        pred_scores, gt_labels, pbox, parea, gbox, gtrig, ggeom,
        cnt, list, nclaims, done, assigned, aMetric, maxM, maxI);
    finalize_kernel<<<dim3(NANCH_BLK), dim3(256), 0, stream>>>(
        gt_bboxes, gt_labels, gt_crowd, cnt, assigned, aMetric, maxM, maxI, out);
}

// Round 11
// 258.717 us; speedup vs baseline: 2.4750x; 1.0769x over previous
//
#include <hip/hip_runtime.h>
#include <math.h>

#pragma clang fp contract(off)

#define BB   8
#define NGT  60
#define LL   21504
#define CC   15
#define KTOP 13
#define BGI  15
#define EPSF 1e-9f
#define LISTCAP 16384
#define NANCH_BLK (BB * LL / 256)  // 672

typedef unsigned long long u64;

// branchless descending compare-swap: ensures a >= b afterwards
#define CS(a, b) { u64 _hi = (b > a) ? b : a; u64 _lo = (b > a) ? a : b; a = _hi; b = _lo; }

// AABB of rotated box, replicating reference _box_min_max op order.
// NOTE: reference QUIRK box (pre-corners (+-w/2*cos, +-h/2*sin)) -- IoU only.
// It does NOT bound the in_gts support (R9 bug); windows use ex/ey below.
__device__ __forceinline__ float4 rbox_aabb(float cx, float cy, float w, float h, float r) {
    float cr = (float)cos((double)r);
    float sr = (float)sin((double)r);
    float dx = (w * 0.5f) * cr;
    float dy = (h * 0.5f) * sr;
    float xs[4] = {cx - dx, cx + dx, cx + dx, cx - dx};
    float ys[4] = {cy - dy, cy - dy, cy + dy, cy + dy};
    float mnx = 1e30f, mxx = -1e30f, mny = 1e30f, mxy = -1e30f;
#pragma unroll
    for (int k = 0; k < 4; ++k) {
        float tx = xs[k] - cx, ty = ys[k] - cy;
        float xr = (cx + tx * cr) - ty * sr;
        float yr = (cy + tx * sr) + ty * cr;
        mnx = fminf(mnx, xr); mxx = fmaxf(mxx, xr);
        mny = fminf(mny, yr); mxy = fmaxf(mxy, yr);
    }
    return make_float4(mnx, mxx, mny, mxy);
}

__device__ __forceinline__ float iou_pair(float4 g, float a1, float4 p, float a2) {
    float iw = fmaxf(fminf(g.y, p.y) - fmaxf(g.x, p.x), 0.0f);
    float ih = fmaxf(fminf(g.w, p.w) - fmaxf(g.z, p.z), 0.0f);
    float inter = iw * ih;
    float denom = ((a1 + a2) - inter) + EPSF;
    float q = inter / denom;
    return fminf(fmaxf(q, 0.0f), 1.0f);
}

// in-gts test, reference op order (anchor coords analytic, exact in fp32)
__device__ __forceinline__ bool in_gts(float apx, float apy, float4 gg, float4 tg) {
    float dx = apx - gg.x, dy = apy - gg.y;
    float xl = dx * tg.x + dy * tg.y;
    float yl = dy * tg.x - dx * tg.y;
    return (fabsf(xl) <= gg.z) && (fabsf(yl) <= gg.w);
}

// ---------- prep: pred boxes (LDS-coalesced), gt state, zero-init ----------
__global__ __launch_bounds__(256) void prep_kernel(
        const float* __restrict__ pr,
        const float* __restrict__ gt,
        const float* __restrict__ pad,
        float4* __restrict__ pbox,
        float* __restrict__ parea,
        float4* __restrict__ gbox,
        float4* __restrict__ gtrig,
        float4* __restrict__ ggeom,
        int* __restrict__ cnt,
        int* __restrict__ nclaims,
        int* __restrict__ done) {
    __shared__ float lds[5 * 257];
    const int t = threadIdx.x;
    const int b = blockIdx.x / (LL / 256);
    const int j0 = (blockIdx.x % (LL / 256)) * 256;
    const int i = blockIdx.x * 256 + t;

    const float* prb = pr + (size_t)(b * LL + j0) * 5;
#pragma unroll
    for (int k = 0; k < 5; ++k) {
        int g = k * 256 + t;
        lds[(g % 5) * 257 + g / 5] = prb[g];
    }
    __syncthreads();
    float cx = lds[0 * 257 + t], cy = lds[1 * 257 + t];
    float w  = lds[2 * 257 + t], h  = lds[3 * 257 + t], r = lds[4 * 257 + t];
    pbox[i]  = rbox_aabb(cx, cy, w, h, r);
    parea[i] = w * h;
    cnt[i] = 0;
    if (i == 0) { *nclaims = 0; *done = 0; }
    if (i < BB * NGT) {
        float gcx = gt[i * 5 + 0], gcy = gt[i * 5 + 1];
        float gw  = gt[i * 5 + 2], gh  = gt[i * 5 + 3], gr = gt[i * 5 + 4];
        gbox[i] = rbox_aabb(gcx, gcy, gw, gh, gr);
        float gcr = (float)cos((double)gr);
        float gsr = (float)sin((double)gr);
        gtrig[i] = make_float4(gcr, gsr, gw * gh, pad[i]);
        ggeom[i] = make_float4(gcx, gcy, gw * 0.5f, gh * 0.5f);
    }
}

// window bounds for one scale (same formulas as R10, validated)
#define WIN(GSZ, ST, CXE, CYE, XL, XH, YL, YH)                                \
    {                                                                         \
        XL = max(0,       (int)floorf((gg.x - (CXE)) / (ST) - 0.5f) - 1);     \
        XH = min((GSZ)-1, (int)ceilf ((gg.x + (CXE)) / (ST) - 0.5f) + 1);     \
        YL = max(0,       (int)floorf((gg.y - (CYE)) / (ST) - 0.5f) - 1);     \
        YH = min((GSZ)-1, (int)ceilf ((gg.y + (CYE)) / (ST) - 0.5f) + 1);     \
    }

// ---------- topk+claims: ONE BLOCK (4 waves) PER ROW, flattened cells ----------
// R10 fix kept (true-support window); R10's latency problem fixed: the 3 scale
// windows are flattened into one cell index, thread-strided -> <=17 cells per
// thread (independent loads), then a 13-round block-wide head merge (wave
// butterfly + 4-entry LDS reduce). Selection values & order bit-identical.
__global__ __launch_bounds__(256) void topk_claim_kernel(
        const float* __restrict__ ps,
        const int* __restrict__ labels,
        const float4* __restrict__ pbox,
        const float* __restrict__ parea,
        const float4* __restrict__ gbox,
        const float4* __restrict__ gtrig,
        const float4* __restrict__ ggeom,
        int* __restrict__ cnt,
        int* __restrict__ list,
        int* __restrict__ nclaims,
        int* __restrict__ done,
        int* __restrict__ assigned,
        float* __restrict__ aMetric,
        unsigned* __restrict__ maxM,
        unsigned* __restrict__ maxI) {
    __shared__ u64 sk[4];
    __shared__ int posjS[KTOP];
    __shared__ int islast;
    __shared__ unsigned mMs[BB * NGT], mIs[BB * NGT];
    const int t = threadIdx.x;
    const int wv = t >> 6, lane = t & 63;
    const int bi = blockIdx.x;                   // one row per block (480)
    const int b = bi / NGT, i = bi % NGT;

    float4 tg = gtrig[bi];
    if (tg.w != 0.0f) {                          // padded rows: no claims (uniform)
        float4 g  = gbox[bi];
        float4 gg = ggeom[bi];
        float  a1 = tg.z;
        const float*  srow = ps + (size_t)b * LL * CC + labels[bi];
        const float4* pb   = pbox + (size_t)b * LL;
        const float*  pa   = parea + (size_t)b * LL;

        // true in_gts support half-extents
        float aco = fabsf(tg.x), asi = fabsf(tg.y);
        float ex = gg.z * aco + gg.w * asi;
        float ey = gg.z * asi + gg.w * aco;

        int xl0, xh0, yl0, yh0, xl1, xh1, yl1, yh1, xl2, xh2, yl2, yh2;
        WIN(128,  8.f, ex, ey, xl0, xh0, yl0, yh0);
        WIN( 64, 16.f, ex, ey, xl1, xh1, yl1, yh1);
        WIN( 32, 32.f, ex, ey, xl2, xh2, yl2, yh2);
        int wx0 = max(0, xh0 - xl0 + 1), wy0 = max(0, yh0 - yl0 + 1);
        int wx1 = max(0, xh1 - xl1 + 1), wy1 = max(0, yh1 - yl1 + 1);
        int wx2 = max(0, xh2 - xl2 + 1), wy2 = max(0, yh2 - yl2 + 1);
        int off1 = wx0 * wy0;
        int off2 = off1 + wx1 * wy1;
        int total = off2 + wx2 * wy2;

        u64 k0 = 0, k1 = 0, k2 = 0, k3 = 0, k4 = 0, k5 = 0, k6 = 0,
            k7 = 0, k8 = 0, k9 = 0, k10 = 0, k11 = 0, k12 = 0;

        for (int c = t; c < total; c += 256) {
            int j; float apx, apy;
            if (c < off1) {
                int iy = c / wx0, ix = c - iy * wx0;
                ix += xl0; iy += yl0;
                j = iy * 128 + ix;
                apx = (ix + 0.5f) * 8.f;  apy = (iy + 0.5f) * 8.f;
            } else if (c < off2) {
                int lc = c - off1;
                int iy = lc / wx1, ix = lc - iy * wx1;
                ix += xl1; iy += yl1;
                j = 16384 + iy * 64 + ix;
                apx = (ix + 0.5f) * 16.f; apy = (iy + 0.5f) * 16.f;
            } else {
                int lc = c - off2;
                int iy = lc / wx2, ix = lc - iy * wx2;
                ix += xl2; iy += yl2;
                j = 20480 + iy * 32 + ix;
                apx = (ix + 0.5f) * 32.f; apy = (iy + 0.5f) * 32.f;
            }
            bool ing = in_gts(apx, apy, gg, tg);
            float4 p = pb[j];
            float a2 = pa[j];
            float iou = iou_pair(g, a1, p, a2);
            float i2 = iou * iou;
            float v = ing ? (srow[(size_t)j * CC] * (i2 * i2 * i2)) : 0.0f;
            if (v > 0.0f) {                      // positives only
                u64 key = ((u64)__float_as_uint(v) << 32) | (unsigned)(~j);
                if (key > k12) {
                    k12 = key;
                    CS(k11, k12); CS(k10, k11); CS(k9, k10); CS(k8, k9);
                    CS(k7, k8);   CS(k6, k7);   CS(k5, k6);  CS(k4, k5);
                    CS(k3, k4);   CS(k2, k3);   CS(k1, k2);  CS(k0, k1);
                }
            }
        }

        // 13-round block-wide head merge; early-exit when winner is 0
        int n_pos = 0;
        for (int r = 0; r < KTOP; ++r) {
            u64 ov = k0;
#pragma unroll
            for (int off = 32; off > 0; off >>= 1) {
                u64 v2 = __shfl_xor(ov, off, 64);
                if (v2 > ov) ov = v2;
            }
            if (lane == 0) sk[wv] = ov;
            __syncthreads();
            u64 bk = sk[0];
#pragma unroll
            for (int k = 1; k < 4; ++k) if (sk[k] > bk) bk = sk[k];
            if (bk == 0) break;                  // block-uniform: no positives left
            if (t == 0) {
                int j = (int)(~(unsigned)bk);
                posjS[n_pos] = j;
                int p2 = b * LL + j;
                atomicAdd(&cnt[p2], 1);
                int slot = atomicAdd(nclaims, 1);
                if (slot < LISTCAP)
                    __hip_atomic_store(&list[slot], (bi << 18) | p2,
                                       __ATOMIC_RELAXED, __HIP_MEMORY_SCOPE_AGENT);
            }
            if (k0 == bk) {                      // unique key -> one thread pops
                k0 = k1; k1 = k2; k2 = k3; k3 = k4; k4 = k5; k5 = k6; k6 = k7;
                k7 = k8; k8 = k9; k9 = k10; k10 = k11; k11 = k12; k12 = 0;
            }
            n_pos++;
            __syncthreads();                     // protect sk for next round
        }

        // zero-metric slots: globally-lowest-index non-positive anchors,
        // claimed iff in-gts (exact reference semantics; R10-validated)
        if (t == 0 && n_pos < KTOP) {
            int need = KTOP - n_pos;
            for (int jz = 0; need > 0 && jz < LL; ++jz) {
                bool isPos = false;
                for (int k = 0; k < n_pos; ++k) isPos |= (posjS[k] == jz);
                if (isPos) continue;
                need--;
                int ix, iy; float st2;
                if (jz < 16384)      { ix = jz & 127; iy = jz >> 7; st2 = 8.f; }
                else if (jz < 20480) { int e = jz - 16384; ix = e & 63; iy = e >> 6; st2 = 16.f; }
                else                 { int e = jz - 20480; ix = e & 31; iy = e >> 5; st2 = 32.f; }
                float apx = (ix + 0.5f) * st2, apy = (iy + 0.5f) * st2;
                if (in_gts(apx, apy, gg, tg)) {
                    int p2 = b * LL + jz;
                    atomicAdd(&cnt[p2], 1);
                    int slot = atomicAdd(nclaims, 1);
                    if (slot < LISTCAP)
                        __hip_atomic_store(&list[slot], (bi << 18) | p2,
                                           __ATOMIC_RELAXED, __HIP_MEMORY_SCOPE_AGENT);
                }
            }
        }
    }

    // ---- elect last block (all claims at MALL via device-scope atomics) ----
    __syncthreads();
    if (t == 0) islast = (atomicAdd(done, 1) == (int)gridDim.x - 1);
    __syncthreads();

    // ---- tail: sparse resolve over the claim list (R10-validated) ----
    if (islast) {
        for (int k = t; k < BB * NGT; k += 256) { mMs[k] = 0u; mIs[k] = 0u; }
        __syncthreads();
        int n = __hip_atomic_load(nclaims, __ATOMIC_RELAXED, __HIP_MEMORY_SCOPE_AGENT);
        n = min(n, LISTCAP);
        for (int e = t; e < n; e += 256) {
            int val = __hip_atomic_load(&list[e], __ATOMIC_RELAXED, __HIP_MEMORY_SCOPE_AGENT);
            int p = val & 0x3FFFF;
            int bic = val >> 18;
            int bb = p / LL;
            int c = __hip_atomic_load(&cnt[p], __ATOMIC_RELAXED, __HIP_MEMORY_SCOPE_AGENT);
            float4 pbv = pbox[p];
            float a2 = parea[p];
            int a; float iouv;
            if (c == 1) {
                a = bic - bb * NGT;
                iouv = iou_pair(gbox[bb * NGT + a], gtrig[bb * NGT + a].z, pbv, a2);
            } else {
                float best = -1.0f; int bsti = 0;
                for (int ii = 0; ii < NGT; ++ii) {
                    float v = iou_pair(gbox[bb * NGT + ii], gtrig[bb * NGT + ii].z, pbv, a2);
                    if (v > best) { best = v; bsti = ii; }   // ties -> lowest index
                }
                a = bsti; iouv = best;
            }
            float sc = ps[(size_t)p * CC + labels[bb * NGT + a]];
            float i2 = iouv * iouv;
            float m = sc * (i2 * i2 * i2);
            assigned[p] = a;                     // consumed next dispatch
            aMetric[p] = m;
            atomicMax(&mMs[bb * NGT + a], __float_as_uint(m));
            atomicMax(&mIs[bb * NGT + a], __float_as_uint(iouv));
        }
        __syncthreads();
        for (int k = t; k < BB * NGT; k += 256) { maxM[k] = mMs[k]; maxI[k] = mIs[k]; }
    }
}

// ---------- finalize: all 5 outputs; strided regions via LDS transpose ----------
__global__ __launch_bounds__(256) void finalize_kernel(
        const float* __restrict__ gt,
        const int* __restrict__ labels,
        const int* __restrict__ crowd,
        const int* __restrict__ cnt,
        const int* __restrict__ assigned,
        const float* __restrict__ aMetric,
        const unsigned* __restrict__ maxM,
        const unsigned* __restrict__ maxI,
        float* __restrict__ out) {
    __shared__ float lds[CC * 257];
    const int t = threadIdx.x;
    const int b = blockIdx.x / (LL / 256);
    const int j0 = (blockIdx.x % (LL / 256)) * 256;
    const int p = blockIdx.x * 256 + t;
    const size_t O0 = 0;
    const size_t O1 = (size_t)BB * LL;
    const size_t O2 = O1 + (size_t)BB * LL * 5;
    const size_t O3 = O2 + (size_t)BB * LL * CC;
    const size_t O4 = O3 + (size_t)BB * LL;

    bool pos = (cnt[p] > 0);
    int idx = pos ? assigned[p] : 0;
    int lab = labels[b * NGT + idx];
    int cw  = crowd[b * NGT + idx];
    out[O0 + p] = pos ? (float)lab : (float)BGI;
    out[O3 + p] = (float)idx;
    out[O4 + p] = (float)cw;
    float per = 0.0f;
    if (pos) {
        float mm = __uint_as_float(maxM[b * NGT + idx]);
        float mi = __uint_as_float(maxI[b * NGT + idx]);
        per = aMetric[p] / (mm + EPSF) * mi;
    }

    // assigned_scores (stride-15) via +1-padded LDS transpose
    float keep = (pos && cw == 0) ? per : 0.0f;
#pragma unroll
    for (int c = 0; c < CC; ++c)
        lds[c * 257 + t] = (c == lab) ? keep : 0.0f;
    __syncthreads();
    float* o2 = out + O2 + (size_t)(b * LL + j0) * CC;
#pragma unroll
    for (int k = 0; k < CC; ++k) {
        int g = k * 256 + t;
        o2[g] = lds[(g % CC) * 257 + g / CC];
    }
    __syncthreads();

    // assigned_rboxes (stride-5) via LDS transpose
    const float* gb = gt + (size_t)(b * NGT + idx) * 5;
#pragma unroll
    for (int k = 0; k < 5; ++k)
        lds[k * 257 + t] = gb[k];
    __syncthreads();
    float* o1 = out + O1 + (size_t)(b * LL + j0) * 5;
#pragma unroll
    for (int k = 0; k < 5; ++k) {
        int g = k * 256 + t;
        o1[g] = lds[(g % 5) * 257 + g / 5];
    }
}

extern "C" void kernel_launch(void* const* d_in, const int* in_sizes, int n_in,
                              void* d_out, int out_size, void* d_ws, size_t ws_size,
                              hipStream_t stream) {
    const float* pred_scores = (const float*)d_in[0];
    const float* pred_rboxes = (const float*)d_in[1];
    // d_in[2] = anchor_points (analytic, unused)
    const int*   gt_labels   = (const int*)d_in[3];
    const float* gt_bboxes   = (const float*)d_in[4];
    // d_in[5] = gt_poses (unused)
    const int*   gt_crowd    = (const int*)d_in[6];
    const float* pad_gt      = (const float*)d_in[7];
    float* out = (float*)d_out;

    char* ws = (char*)d_ws;
    size_t off = 0;
    auto alloc = [&](size_t bytes) {
        void* pp = ws + off;
        off += (bytes + 255) & ~(size_t)255;
        return pp;
    };
    float4* pbox  = (float4*)alloc((size_t)BB * LL * 16);
    float*  parea = (float*)alloc((size_t)BB * LL * 4);
    float4* gbox  = (float4*)alloc((size_t)BB * NGT * 16);
    float4* gtrig = (float4*)alloc((size_t)BB * NGT * 16);
    float4* ggeom = (float4*)alloc((size_t)BB * NGT * 16);
    int* cnt        = (int*)alloc((size_t)BB * LL * 4);
    int*   assigned = (int*)alloc((size_t)BB * LL * 4);
    float* aMetric  = (float*)alloc((size_t)BB * LL * 4);
    unsigned* maxM  = (unsigned*)alloc((size_t)BB * NGT * 4);
    unsigned* maxI  = (unsigned*)alloc((size_t)BB * NGT * 4);
    int* list       = (int*)alloc((size_t)LISTCAP * 4);
    int* nclaims    = (int*)alloc(256);
    int* done       = (int*)alloc(256);

    prep_kernel<<<dim3(NANCH_BLK), dim3(256), 0, stream>>>(
        pred_rboxes, gt_bboxes, pad_gt,
        pbox, parea, gbox, gtrig, ggeom, cnt, nclaims, done);
    topk_claim_kernel<<<dim3(BB * NGT), dim3(256), 0, stream>>>(
        pred_scores, gt_labels, pbox, parea, gbox, gtrig, ggeom,
        cnt, list, nclaims, done, assigned, aMetric, maxM, maxI);
    finalize_kernel<<<dim3(NANCH_BLK), dim3(256), 0, stream>>>(
        gt_bboxes, gt_labels, gt_crowd, cnt, assigned, aMetric, maxM, maxI, out);
}

// Round 12
// 160.311 us; speedup vs baseline: 3.9943x; 1.6138x over previous
//
#include <hip/hip_runtime.h>
#include <math.h>

#pragma clang fp contract(off)

#define BB   8
#define NGT  60
#define LL   21504
#define CC   15
#define KTOP 13
#define BGI  15
#define EPSF 1e-9f
#define LISTCAP 16384
#define NANCH_BLK (BB * LL / 256)  // 672
#define NBLK 480                   // mega grid: guaranteed co-resident (<=512)
#define SPIN_MAX 100000            // bounded spin: fail, never hang

typedef unsigned long long u64;

// branchless descending compare-swap: ensures a >= b afterwards
#define CS(a, b) { u64 _hi = (b > a) ? b : a; u64 _lo = (b > a) ? a : b; a = _hi; b = _lo; }

__device__ __forceinline__ int aload_i(const int* p) {
    return __hip_atomic_load(p, __ATOMIC_RELAXED, __HIP_MEMORY_SCOPE_AGENT);
}
__device__ __forceinline__ unsigned aload_u(const unsigned* p) {
    return __hip_atomic_load(p, __ATOMIC_RELAXED, __HIP_MEMORY_SCOPE_AGENT);
}
__device__ __forceinline__ float aload_f(const float* p) {
    return __hip_atomic_load(p, __ATOMIC_RELAXED, __HIP_MEMORY_SCOPE_AGENT);
}

// Fence-free spin barrier. Prior writes are all MALL-coherent atomic ops that
// COMPLETE before s_barrier (compiler drains vmcnt at __syncthreads), so no
// release/acquire (= no per-block wbl2/inv, the R8 tax) is needed. Readers on
// the far side use agent-scope atomic loads, which always see MALL.
__device__ __forceinline__ void spin_barrier(int* ctr) {
    __syncthreads();
    if (threadIdx.x == 0) {
        __hip_atomic_fetch_add(ctr, 1, __ATOMIC_RELAXED, __HIP_MEMORY_SCOPE_AGENT);
        int spins = 0;
        while (__hip_atomic_load(ctr, __ATOMIC_RELAXED, __HIP_MEMORY_SCOPE_AGENT) < NBLK) {
            if (++spins > SPIN_MAX) break;
            __builtin_amdgcn_s_sleep(4);
        }
    }
    __syncthreads();
}

// AABB of rotated box, replicating reference _box_min_max op order.
// NOTE: reference QUIRK box -- IoU only; does NOT bound in_gts support.
__device__ __forceinline__ float4 rbox_aabb(float cx, float cy, float w, float h, float r) {
    float cr = (float)cos((double)r);
    float sr = (float)sin((double)r);
    float dx = (w * 0.5f) * cr;
    float dy = (h * 0.5f) * sr;
    float xs[4] = {cx - dx, cx + dx, cx + dx, cx - dx};
    float ys[4] = {cy - dy, cy - dy, cy + dy, cy + dy};
    float mnx = 1e30f, mxx = -1e30f, mny = 1e30f, mxy = -1e30f;
#pragma unroll
    for (int k = 0; k < 4; ++k) {
        float tx = xs[k] - cx, ty = ys[k] - cy;
        float xr = (cx + tx * cr) - ty * sr;
        float yr = (cy + tx * sr) + ty * cr;
        mnx = fminf(mnx, xr); mxx = fmaxf(mxx, xr);
        mny = fminf(mny, yr); mxy = fmaxf(mxy, yr);
    }
    return make_float4(mnx, mxx, mny, mxy);
}

__device__ __forceinline__ float iou_pair(float4 g, float a1, float4 p, float a2) {
    float iw = fmaxf(fminf(g.y, p.y) - fmaxf(g.x, p.x), 0.0f);
    float ih = fmaxf(fminf(g.w, p.w) - fmaxf(g.z, p.z), 0.0f);
    float inter = iw * ih;
    float denom = ((a1 + a2) - inter) + EPSF;
    float q = inter / denom;
    return fminf(fmaxf(q, 0.0f), 1.0f);
}

// in-gts test, reference op order (anchor coords analytic, exact in fp32)
__device__ __forceinline__ bool in_gts(float apx, float apy, float4 gg, float4 tg) {
    float dx = apx - gg.x, dy = apy - gg.y;
    float xl = dx * tg.x + dy * tg.y;
    float yl = dy * tg.x - dx * tg.y;
    return (fabsf(xl) <= gg.z) && (fabsf(yl) <= gg.w);
}

// ---------- prep: pred boxes (LDS-coalesced), gt state, zero-init ----------
__global__ __launch_bounds__(256) void prep_kernel(
        const float* __restrict__ pr,
        const float* __restrict__ gt,
        const float* __restrict__ pad,
        float4* __restrict__ pbox,
        float* __restrict__ parea,
        float4* __restrict__ gbox,
        float4* __restrict__ gtrig,
        float4* __restrict__ ggeom,
        int* __restrict__ cnt,
        unsigned* __restrict__ maxM,
        unsigned* __restrict__ maxI,
        int* __restrict__ nclaims,
        int* __restrict__ done1,
        int* __restrict__ done2) {
    __shared__ float lds[5 * 257];
    const int t = threadIdx.x;
    const int b = blockIdx.x / (LL / 256);
    const int j0 = (blockIdx.x % (LL / 256)) * 256;
    const int i = blockIdx.x * 256 + t;

    const float* prb = pr + (size_t)(b * LL + j0) * 5;
#pragma unroll
    for (int k = 0; k < 5; ++k) {
        int g = k * 256 + t;
        lds[(g % 5) * 257 + g / 5] = prb[g];
    }
    __syncthreads();
    float cx = lds[0 * 257 + t], cy = lds[1 * 257 + t];
    float w  = lds[2 * 257 + t], h  = lds[3 * 257 + t], r = lds[4 * 257 + t];
    pbox[i]  = rbox_aabb(cx, cy, w, h, r);
    parea[i] = w * h;
    cnt[i] = 0;
    if (i == 0) { *nclaims = 0; *done1 = 0; *done2 = 0; }
    if (i < BB * NGT) {
        float gcx = gt[i * 5 + 0], gcy = gt[i * 5 + 1];
        float gw  = gt[i * 5 + 2], gh  = gt[i * 5 + 3], gr = gt[i * 5 + 4];
        gbox[i] = rbox_aabb(gcx, gcy, gw, gh, gr);
        float gcr = (float)cos((double)gr);
        float gsr = (float)sin((double)gr);
        gtrig[i] = make_float4(gcr, gsr, gw * gh, pad[i]);
        ggeom[i] = make_float4(gcx, gcy, gw * 0.5f, gh * 0.5f);
        maxM[i] = 0u; maxI[i] = 0u;
    }
}

// window bounds for one scale (R10/R11-validated)
#define WIN(GSZ, ST, XL, XH, YL, YH)                                          \
    {                                                                         \
        XL = max(0,       (int)floorf((gg.x - ex) / (ST) - 0.5f) - 1);        \
        XH = min((GSZ)-1, (int)ceilf ((gg.x + ex) / (ST) - 0.5f) + 1);        \
        YL = max(0,       (int)floorf((gg.y - ey) / (ST) - 0.5f) - 1);        \
        YH = min((GSZ)-1, (int)ceilf ((gg.y + ey) / (ST) - 0.5f) + 1);        \
    }

// ---------- mega: topk+claims -> barrier -> PARALLEL resolve -> barrier ->
//            finalize (grid-stride). One block per GT row (480 blocks). ----------
__global__ __launch_bounds__(256, 2) void mega_kernel(
        const float* __restrict__ ps,
        const int* __restrict__ labels,
        const int* __restrict__ crowd,
        const float* __restrict__ gt,
        const float4* __restrict__ pbox,
        const float* __restrict__ parea,
        const float4* __restrict__ gbox,
        const float4* __restrict__ gtrig,
        const float4* __restrict__ ggeom,
        int* __restrict__ cnt,
        int* __restrict__ list,
        int* __restrict__ nclaims,
        int* __restrict__ done1,
        int* __restrict__ done2,
        int* __restrict__ assigned,
        float* __restrict__ aMetric,
        unsigned* __restrict__ maxM,
        unsigned* __restrict__ maxI,
        float* __restrict__ out) {
    __shared__ float lds[CC * 257];
    __shared__ u64 sk[4];
    __shared__ int posjS[KTOP];
    const int t = threadIdx.x;
    const int wv = t >> 6, lane = t & 63;
    const int bi = blockIdx.x;                   // one row per block
    const int b = bi / NGT, i = bi % NGT;

    // ========== Phase A: windowed scan + top-13 + claims (R11-validated) ==========
    float4 tg = gtrig[bi];
    if (tg.w != 0.0f) {
        float4 g  = gbox[bi];
        float4 gg = ggeom[bi];
        float  a1 = tg.z;
        const float*  srow = ps + (size_t)b * LL * CC + labels[bi];
        const float4* pb   = pbox + (size_t)b * LL;
        const float*  pa   = parea + (size_t)b * LL;

        float aco = fabsf(tg.x), asi = fabsf(tg.y);
        float ex = gg.z * aco + gg.w * asi;       // true in_gts support
        float ey = gg.z * asi + gg.w * aco;

        int xl0, xh0, yl0, yh0, xl1, xh1, yl1, yh1, xl2, xh2, yl2, yh2;
        WIN(128,  8.f, xl0, xh0, yl0, yh0);
        WIN( 64, 16.f, xl1, xh1, yl1, yh1);
        WIN( 32, 32.f, xl2, xh2, yl2, yh2);
        int wx0 = max(0, xh0 - xl0 + 1), wy0 = max(0, yh0 - yl0 + 1);
        int wx1 = max(0, xh1 - xl1 + 1), wy1 = max(0, yh1 - yl1 + 1);
        int wx2 = max(0, xh2 - xl2 + 1), wy2 = max(0, yh2 - yl2 + 1);
        int off1 = wx0 * wy0;
        int off2 = off1 + wx1 * wy1;
        int total = off2 + wx2 * wy2;

        u64 k0 = 0, k1 = 0, k2 = 0, k3 = 0, k4 = 0, k5 = 0, k6 = 0,
            k7 = 0, k8 = 0, k9 = 0, k10 = 0, k11 = 0, k12 = 0;

        for (int c = t; c < total; c += 256) {
            int j; float apx, apy;
            if (c < off1) {
                int iy = c / wx0, ix = c - iy * wx0;
                ix += xl0; iy += yl0;
                j = iy * 128 + ix;
                apx = (ix + 0.5f) * 8.f;  apy = (iy + 0.5f) * 8.f;
            } else if (c < off2) {
                int lc = c - off1;
                int iy = lc / wx1, ix = lc - iy * wx1;
                ix += xl1; iy += yl1;
                j = 16384 + iy * 64 + ix;
                apx = (ix + 0.5f) * 16.f; apy = (iy + 0.5f) * 16.f;
            } else {
                int lc = c - off2;
                int iy = lc / wx2, ix = lc - iy * wx2;
                ix += xl2; iy += yl2;
                j = 20480 + iy * 32 + ix;
                apx = (ix + 0.5f) * 32.f; apy = (iy + 0.5f) * 32.f;
            }
            bool ing = in_gts(apx, apy, gg, tg);
            float4 p = pb[j];
            float a2 = pa[j];
            float iou = iou_pair(g, a1, p, a2);
            float i2 = iou * iou;
            float v = ing ? (srow[(size_t)j * CC] * (i2 * i2 * i2)) : 0.0f;
            if (v > 0.0f) {
                u64 key = ((u64)__float_as_uint(v) << 32) | (unsigned)(~j);
                if (key > k12) {
                    k12 = key;
                    CS(k11, k12); CS(k10, k11); CS(k9, k10); CS(k8, k9);
                    CS(k7, k8);   CS(k6, k7);   CS(k5, k6);  CS(k4, k5);
                    CS(k3, k4);   CS(k2, k3);   CS(k1, k2);  CS(k0, k1);
                }
            }
        }

        // 13-round block-wide head merge; early-exit when winner is 0
        int n_pos = 0;
        for (int r = 0; r < KTOP; ++r) {
            u64 ov = k0;
#pragma unroll
            for (int off = 32; off > 0; off >>= 1) {
                u64 v2 = __shfl_xor(ov, off, 64);
                if (v2 > ov) ov = v2;
            }
            if (lane == 0) sk[wv] = ov;
            __syncthreads();
            u64 bk = sk[0];
#pragma unroll
            for (int k = 1; k < 4; ++k) if (sk[k] > bk) bk = sk[k];
            if (bk == 0) break;                  // block-uniform
            if (t == 0) {
                int j = (int)(~(unsigned)bk);
                posjS[n_pos] = j;
                int p2 = b * LL + j;
                atomicAdd(&cnt[p2], 1);          // device scope -> MALL
                int slot = atomicAdd(nclaims, 1);
                if (slot < LISTCAP)
                    __hip_atomic_store(&list[slot], (bi << 18) | p2,
                                       __ATOMIC_RELAXED, __HIP_MEMORY_SCOPE_AGENT);
            }
            if (k0 == bk) {                      // unique key -> one thread pops
                k0 = k1; k1 = k2; k2 = k3; k3 = k4; k4 = k5; k5 = k6; k6 = k7;
                k7 = k8; k8 = k9; k9 = k10; k10 = k11; k11 = k12; k12 = 0;
            }
            n_pos++;
            __syncthreads();
        }

        // zero-metric slots: globally-lowest-index non-positive anchors,
        // claimed iff in-gts (R10/R11-validated exact top_k emulation)
        if (t == 0 && n_pos < KTOP) {
            int need = KTOP - n_pos;
            for (int jz = 0; need > 0 && jz < LL; ++jz) {
                bool isPos = false;
                for (int k = 0; k < n_pos; ++k) isPos |= (posjS[k] == jz);
                if (isPos) continue;
                need--;
                int ix, iy; float st2;
                if (jz < 16384)      { ix = jz & 127; iy = jz >> 7; st2 = 8.f; }
                else if (jz < 20480) { int e = jz - 16384; ix = e & 63; iy = e >> 6; st2 = 16.f; }
                else                 { int e = jz - 20480; ix = e & 31; iy = e >> 5; st2 = 32.f; }
                float apx = (ix + 0.5f) * st2, apy = (iy + 0.5f) * st2;
                if (in_gts(apx, apy, gg, tg)) {
                    int p2 = b * LL + jz;
                    atomicAdd(&cnt[p2], 1);
                    int slot = atomicAdd(nclaims, 1);
                    if (slot < LISTCAP)
                        __hip_atomic_store(&list[slot], (bi << 18) | p2,
                                           __ATOMIC_RELAXED, __HIP_MEMORY_SCOPE_AGENT);
                }
            }
        }
    }

    spin_barrier(done1);

    // ========== Phase B: PARALLEL sparse resolve (1 claim per thread) ==========
    {
        int n = min(aload_i(nclaims), LISTCAP);
        int e = bi * 256 + t;                    // 122880 threads >= n
        if (e < n) {
            int val = aload_i(&list[e]);
            int p = val & 0x3FFFF;
            int bic = val >> 18;
            int bb = p / LL;
            int c = aload_i(&cnt[p]);
            float4 pbv = pbox[p];
            float a2 = parea[p];
            int a; float iouv;
            if (c == 1) {
                a = bic - bb * NGT;
                iouv = iou_pair(gbox[bb * NGT + a], gtrig[bb * NGT + a].z, pbv, a2);
            } else {                             // duplicates write identically
                float best = -1.0f; int bsti = 0;
                for (int ii = 0; ii < NGT; ++ii) {
                    float v = iou_pair(gbox[bb * NGT + ii], gtrig[bb * NGT + ii].z, pbv, a2);
                    if (v > best) { best = v; bsti = ii; }   // ties -> lowest index
                }
                a = bsti; iouv = best;
            }
            float sc = ps[(size_t)p * CC + labels[bb * NGT + a]];
            float i2 = iouv * iouv;
            float m = sc * (i2 * i2 * i2);
            __hip_atomic_store(&assigned[p], a, __ATOMIC_RELAXED, __HIP_MEMORY_SCOPE_AGENT);
            __hip_atomic_store(&aMetric[p], m, __ATOMIC_RELAXED, __HIP_MEMORY_SCOPE_AGENT);
            atomicMax(&maxM[bb * NGT + a], __float_as_uint(m));
            atomicMax(&maxI[bb * NGT + a], __float_as_uint(iouv));
        }
    }

    spin_barrier(done2);

    // ========== Phase C: finalize, grid-stride over 672 anchor tiles ==========
    for (int it = 0; it < 2; ++it) {
        int tile = bi + it * NBLK;
        if (tile >= NANCH_BLK) continue;         // block-uniform
        __syncthreads();                         // lds reuse guard
        const int fb = tile / (LL / 256);
        const int j0 = (tile % (LL / 256)) * 256;
        const int p = tile * 256 + t;
        const size_t O0 = 0;
        const size_t O1 = (size_t)BB * LL;
        const size_t O2 = O1 + (size_t)BB * LL * 5;
        const size_t O3 = O2 + (size_t)BB * LL * CC;
        const size_t O4 = O3 + (size_t)BB * LL;

        bool pos = aload_i(&cnt[p]) > 0;
        int idx = 0; float per = 0.0f;
        if (pos) {
            idx = aload_i(&assigned[p]);
            float mm = __uint_as_float(aload_u(&maxM[fb * NGT + idx]));
            float mi = __uint_as_float(aload_u(&maxI[fb * NGT + idx]));
            per = aload_f(&aMetric[p]) / (mm + EPSF) * mi;
        }
        int lab = labels[fb * NGT + idx];
        int cw  = crowd[fb * NGT + idx];
        out[O0 + p] = pos ? (float)lab : (float)BGI;
        out[O3 + p] = (float)idx;
        out[O4 + p] = (float)cw;

        // assigned_scores (stride-15) via +1-padded LDS transpose
        float keep = (pos && cw == 0) ? per : 0.0f;
#pragma unroll
        for (int c = 0; c < CC; ++c)
            lds[c * 257 + t] = (c == lab) ? keep : 0.0f;
        __syncthreads();
        float* o2 = out + O2 + (size_t)(fb * LL + j0) * CC;
#pragma unroll
        for (int k = 0; k < CC; ++k) {
            int g = k * 256 + t;
            o2[g] = lds[(g % CC) * 257 + g / CC];
        }
        __syncthreads();

        // assigned_rboxes (stride-5) via LDS transpose
        const float* gb = gt + (size_t)(fb * NGT + idx) * 5;
#pragma unroll
        for (int k = 0; k < 5; ++k)
            lds[k * 257 + t] = gb[k];
        __syncthreads();
        float* o1 = out + O1 + (size_t)(fb * LL + j0) * 5;
#pragma unroll
        for (int k = 0; k < 5; ++k) {
            int g = k * 256 + t;
            o1[g] = lds[(g % 5) * 257 + g / 5];
        }
    }
}

extern "C" void kernel_launch(void* const* d_in, const int* in_sizes, int n_in,
                              void* d_out, int out_size, void* d_ws, size_t ws_size,
                              hipStream_t stream) {
    const float* pred_scores = (const float*)d_in[0];
    const float* pred_rboxes = (const float*)d_in[1];
    // d_in[2] = anchor_points (analytic, unused)
    const int*   gt_labels   = (const int*)d_in[3];
    const float* gt_bboxes   = (const float*)d_in[4];
    // d_in[5] = gt_poses (unused)
    const int*   gt_crowd    = (const int*)d_in[6];
    const float* pad_gt      = (const float*)d_in[7];
    float* out = (float*)d_out;

    char* ws = (char*)d_ws;
    size_t off = 0;
    auto alloc = [&](size_t bytes) {
        void* pp = ws + off;
        off += (bytes + 255) & ~(size_t)255;
        return pp;
    };
    float4* pbox  = (float4*)alloc((size_t)BB * LL * 16);
    float*  parea = (float*)alloc((size_t)BB * LL * 4);
    float4* gbox  = (float4*)alloc((size_t)BB * NGT * 16);
    float4* gtrig = (float4*)alloc((size_t)BB * NGT * 16);
    float4* ggeom = (float4*)alloc((size_t)BB * NGT * 16);
    int* cnt        = (int*)alloc((size_t)BB * LL * 4);
    int*   assigned = (int*)alloc((size_t)BB * LL * 4);
    float* aMetric  = (float*)alloc((size_t)BB * LL * 4);
    unsigned* maxM  = (unsigned*)alloc((size_t)BB * NGT * 4);
    unsigned* maxI  = (unsigned*)alloc((size_t)BB * NGT * 4);
    int* list       = (int*)alloc((size_t)LISTCAP * 4);
    int* nclaims    = (int*)alloc(256);
    int* done1      = (int*)alloc(256);
    int* done2      = (int*)alloc(256);

    prep_kernel<<<dim3(NANCH_BLK), dim3(256), 0, stream>>>(
        pred_rboxes, gt_bboxes, pad_gt,
        pbox, parea, gbox, gtrig, ggeom, cnt, maxM, maxI, nclaims, done1, done2);
    mega_kernel<<<dim3(NBLK), dim3(256), 0, stream>>>(
        pred_scores, gt_labels, gt_crowd, gt_bboxes,
        pbox, parea, gbox, gtrig, ggeom,
        cnt, list, nclaims, done1, done2,
        assigned, aMetric, maxM, maxI, out);
}